// Round 10
// baseline (330.021 us; speedup 1.0000x reference)
//
#include <hip/hip_runtime.h>

#define N_SUM 2048
#define HIDD 128
#define NEDGE 16384
#define ROWS (N_SUM * 64)
#define NSLOT 32

typedef short short8 __attribute__((ext_vector_type(8)));
typedef float floatx4 __attribute__((ext_vector_type(4)));
typedef unsigned int uint4n __attribute__((ext_vector_type(4)));
typedef unsigned short ushort_t;

__device__ __forceinline__ ushort_t f2bf(float f) {
    unsigned u = __builtin_bit_cast(unsigned, f);
    u += 0x7fffu + ((u >> 16) & 1u);   // RNE
    return (ushort_t)(u >> 16);
}
__device__ __forceinline__ float bf2f(ushort_t h) {
    return __builtin_bit_cast(float, (unsigned)h << 16);
}
__device__ __forceinline__ void unpack8(uint4 v, float* f) {
    f[0] = bf2f(v.x & 0xffff); f[1] = bf2f(v.x >> 16);
    f[2] = bf2f(v.y & 0xffff); f[3] = bf2f(v.y >> 16);
    f[4] = bf2f(v.z & 0xffff); f[5] = bf2f(v.z >> 16);
    f[6] = bf2f(v.w & 0xffff); f[7] = bf2f(v.w >> 16);
}
__device__ __forceinline__ uint4 pack8(const float* f) {
    uint4 v;
    v.x = f2bf(f[0]) | ((unsigned)f2bf(f[1]) << 16);
    v.y = f2bf(f[2]) | ((unsigned)f2bf(f[3]) << 16);
    v.z = f2bf(f[4]) | ((unsigned)f2bf(f[5]) << 16);
    v.w = f2bf(f[6]) | ((unsigned)f2bf(f[7]) << 16);
    return v;
}
__device__ __forceinline__ void nt_store16(const void* src, void* dst) {
    __builtin_nontemporal_store(*(const uint4n*)src, (uint4n*)dst);
}

// ---------------- mega prep: CSR (block 0) + weight prep + sums zero, ONE dispatch ----------------
// block 0          : CSR build via LDS atomics (count -> scan -> fill)
// blocks 1..50     : w1t0 / w2lt / bvec (prep_small)
// blocks 51..242   : w21t = W2m @ W1r in B-fragment layout (prep_w21)
// blocks 243..258  : zero sums (4 layers x NSLOT x 256 floats)
__global__ __launch_bounds__(256) void mega_prep(const int* __restrict__ src, const int* __restrict__ dst,
                                                 const float* __restrict__ W1f, const float* __restrict__ W2l,
                                                 const float* __restrict__ b2m, const float* __restrict__ W1r,
                                                 const float* __restrict__ W2m,
                                                 int* __restrict__ irp, int* __restrict__ icol,
                                                 ushort_t* __restrict__ w1t0, ushort_t* __restrict__ w2lt,
                                                 float* __restrict__ bvec, ushort_t* __restrict__ w21t,
                                                 float* __restrict__ sums) {
    __shared__ int sdeg[2048];
    __shared__ int scur[2048];
    __shared__ int csum[256];
    int tid = threadIdx.x, blk = blockIdx.x;

    if (blk == 0) {
        for (int i = tid; i < 2048; i += 256) sdeg[i] = 0;
        __syncthreads();
        for (int e = tid; e < NEDGE; e += 256) atomicAdd(&sdeg[dst[e]], 1);
        __syncthreads();
        int loc[8], s = 0;
#pragma unroll
        for (int q = 0; q < 8; q++) { loc[q] = s; s += sdeg[tid * 8 + q]; }
        csum[tid] = s;
        __syncthreads();
        for (int off = 1; off < 256; off <<= 1) {
            int v = (tid >= off) ? csum[tid - off] : 0;
            __syncthreads();
            csum[tid] += v;
            __syncthreads();
        }
        int base = (tid == 0) ? 0 : csum[tid - 1];
#pragma unroll
        for (int q = 0; q < 8; q++) {
            int node = tid * 8 + q;
            int rpv = base + loc[q];
            irp[node] = rpv;
            scur[node] = rpv;
        }
        if (tid == 255) irp[2048] = csum[255];
        __syncthreads();
        for (int e = tid; e < NEDGE; e += 256) {
            int d = dst[e];
            int pos = atomicAdd(&scur[d], 1);
            icol[pos] = src[e];
        }
    } else if (blk <= 50) {
        int idx = (blk - 1) * 256 + tid;
        if (idx < 4096) {
            int nn = idx >> 5, k = idx & 31;
            w1t0[idx] = f2bf(k < 16 ? W1f[k * 128 + nn] : 0.f);
        } else if (idx < 4096 + 8192) {
            int r = idx - 4096;
            int nn = r >> 7, k = r & 127;
            w2lt[r] = f2bf(W2l[k * 64 + nn]);
        } else if (idx < 4096 + 8192 + 384) {
            int r = idx - 12288;
            int lm = r >> 7, c = r & 127;
            float s = 0.f;
            for (int o = 0; o < 128; o++) s += b2m[lm * 128 + o] * W1r[(size_t)lm * 16384 + o * 128 + c];
            bvec[r] = s;
        }
    } else if (blk <= 242) {
        int idx = (blk - 51) * 256 + tid;  // 49152 total
        int lm = idx >> 14, r = idx & 16383, i = r >> 7, c = r & 127;
        const float* w2row = W2m + (size_t)lm * 16384 + i * 128;
        const float* w1col = W1r + (size_t)lm * 16384 + c;
        float s = 0.f;
#pragma unroll 8
        for (int o = 0; o < 128; o++) s += w2row[o] * w1col[o * 128];
        w21t[(size_t)lm * 16384 + c * 128 + i] = f2bf(s);
    } else {
        int idx = (blk - 243) * 256 + tid;  // 4096 threads x 8 = 32768
#pragma unroll
        for (int q = 0; q < 8; q++) sums[idx * 8 + q] = 0.f;
    }
}

// A-layout for a 64x128 bf16 tile: elem(m, k) at ((k>>3)*64 + m)*8 + (k&7)

// ---------------- layer 0: gather fp32 W + MFMA (K=16 padded to 32) ----------------
__global__ __launch_bounds__(256, 4) void gin_mm1_l0(const float* __restrict__ Xf, const ushort_t* __restrict__ W1t,
                                                     const float* __restrict__ b1, const float* __restrict__ eps,
                                                     const int* __restrict__ rp, const int* __restrict__ colv,
                                                     ushort_t* __restrict__ H, float* __restrict__ sums) {
    __shared__ ushort_t Zs[64 * 128];  // 16 KB
    int tid = threadIdx.x, n = blockIdx.x;
    float ev = 1.0f + eps[0];
    int e0 = rp[n], e1 = rp[n + 1], deg = e1 - e0;
    const float4* X = (const float4*)Xf;

    float4 sA, sB;
    sA = X[(size_t)n * 256 + tid];
    if (deg > 0) sB = X[(size_t)colv[e0] * 256 + tid];
    float4 a;
    a.x = sA.x * ev; a.y = sA.y * ev; a.z = sA.z * ev; a.w = sA.w * ev;
    int i = 1;
    for (; i + 1 < deg; i += 2) {
        sA = X[(size_t)colv[e0 + i] * 256 + tid];
        a.x += sB.x; a.y += sB.y; a.z += sB.z; a.w += sB.w;
        sB = X[(size_t)colv[e0 + i + 1] * 256 + tid];
        a.x += sA.x; a.y += sA.y; a.z += sA.z; a.w += sA.w;
    }
    if (deg > 0) {
        if (i < deg) {
            sA = X[(size_t)colv[e0 + i] * 256 + tid];
            a.x += sB.x; a.y += sB.y; a.z += sB.z; a.w += sB.w;
            a.x += sA.x; a.y += sA.y; a.z += sA.z; a.w += sA.w;
        } else {
            a.x += sB.x; a.y += sB.y; a.z += sB.z; a.w += sB.w;
        }
    }

    {
        int m = tid >> 2, k0 = (tid & 3) * 4;
        int addr = ((k0 >> 3) * 64 + m) * 8 + (k0 & 7);
        uint2 pv;
        pv.x = f2bf(a.x) | ((unsigned)f2bf(a.y) << 16);
        pv.y = f2bf(a.z) | ((unsigned)f2bf(a.w) << 16);
        *(uint2*)&Zs[addr] = pv;
        *(uint2*)&Zs[1024 + tid * 4] = make_uint2(0u, 0u);
    }
    __syncthreads();

    int w = tid >> 6, lane = tid & 63, lg = lane >> 4, ln = lane & 15;
    floatx4 C[4][2];
#pragma unroll
    for (int mt = 0; mt < 4; mt++) { C[mt][0] = {0.f, 0.f, 0.f, 0.f}; C[mt][1] = {0.f, 0.f, 0.f, 0.f}; }

    {
        short8 B0 = *(const short8*)&W1t[(w * 32 + ln) * 32 + lg * 8];
        short8 B1 = *(const short8*)&W1t[(w * 32 + 16 + ln) * 32 + lg * 8];
#pragma unroll
        for (int mt = 0; mt < 4; mt++) {
            short8 A = *(const short8*)&Zs[(lg * 64 + mt * 16 + ln) * 8];
            C[mt][0] = __builtin_amdgcn_mfma_f32_16x16x32_bf16(A, B0, C[mt][0], 0, 0, 0);
            C[mt][1] = __builtin_amdgcn_mfma_f32_16x16x32_bf16(A, B1, C[mt][1], 0, 0, 0);
        }
    }

    float bsum[2], bsq[2];
    float bv[2] = {b1[w * 32 + ln], b1[w * 32 + 16 + ln]};
#pragma unroll
    for (int nt = 0; nt < 2; nt++) {
        float s = 0.f, s2 = 0.f;
#pragma unroll
        for (int mt = 0; mt < 4; mt++)
#pragma unroll
            for (int r = 0; r < 4; r++) {
                float v = C[mt][nt][r] + bv[nt];
                C[mt][nt][r] = v;
                s += v; s2 += v * v;
            }
        bsum[nt] = s; bsq[nt] = s2;
    }
#pragma unroll
    for (int nt = 0; nt < 2; nt++) {
        bsum[nt] += __shfl_xor(bsum[nt], 16, 64);
        bsum[nt] += __shfl_xor(bsum[nt], 32, 64);
        bsq[nt] += __shfl_xor(bsq[nt], 16, 64);
        bsq[nt] += __shfl_xor(bsq[nt], 32, 64);
    }
    if (lg == 0) {
        float* sl = sums + (n & (NSLOT - 1)) * 256;
        int c0 = w * 32 + ln;
        atomicAdd(&sl[c0], bsum[0]);
        atomicAdd(&sl[c0 + 16], bsum[1]);
        atomicAdd(&sl[128 + c0], bsq[0]);
        atomicAdd(&sl[128 + c0 + 16], bsq[1]);
    }
    __syncthreads();
#pragma unroll
    for (int nt = 0; nt < 2; nt++) {
        int colc = w * 32 + nt * 16 + ln;
        int base = (colc >> 3) * 512 + (colc & 7);
#pragma unroll
        for (int mt = 0; mt < 4; mt++)
#pragma unroll
            for (int r = 0; r < 4; r++) {
                int row = mt * 16 + lg * 4 + r;
                Zs[base + row * 8] = f2bf(C[mt][nt][r]);
            }
    }
    __syncthreads();
#pragma unroll
    for (int q = 0; q < 4; q++)
        nt_store16(&((const uint4*)Zs)[q * 256 + tid], &((uint4*)&H[(size_t)n * 8192])[q * 256 + tid]);
}

// ---------------- fused layers 1..3: HALF-NODE blocks (grid 4096 x 256 thr) ----------------
// Block (n, h) gathers rows m in [h*32, h*32+32) of relu(bn(Hin)) over self+edges,
// computes those 32 rows of H = Z @ W21 + (b1 + (1+eps+deg)*bvec); slot-replicated BN sums.
__global__ __launch_bounds__(256, 6) void gin_mm1_fused(const ushort_t* __restrict__ Hin,
                                                        const ushort_t* __restrict__ W21t,
                                                        const float* __restrict__ b1, const float* __restrict__ bvec,
                                                        const float* __restrict__ sums_prev,
                                                        const float* __restrict__ gam_prev,
                                                        const float* __restrict__ bet_prev,
                                                        const float* __restrict__ epsp,
                                                        const int* __restrict__ rp, const int* __restrict__ colv,
                                                        ushort_t* __restrict__ Hout, float* __restrict__ sums_cur) {
    __shared__ ushort_t Zs[32 * 128];   // 8 KB (half slab, A-layout with 32-row k-groups)
    __shared__ float scs_lds[256];      // 1 KB
    int tid = threadIdx.x;
    int n = blockIdx.x >> 1, h = blockIdx.x & 1;

    if (tid < 128) {
        float s = 0.f, s2 = 0.f;
#pragma unroll
        for (int k = 0; k < NSLOT; k++) {
            s += sums_prev[k * 256 + tid];
            s2 += sums_prev[k * 256 + 128 + tid];
        }
        float mean = s * (1.f / (float)ROWS);
        float var = s2 * (1.f / (float)ROWS) - mean * mean;
        float sc = gam_prev[tid] * rsqrtf(var + 1e-5f);
        scs_lds[tid] = sc;
        scs_lds[128 + tid] = bet_prev[tid] - mean * sc;
    }
    __syncthreads();

    // packed BN params for this thread's 2 chunks; chunk q covers cols kg*8+j, kg = (q*256+tid)>>5
    unsigned scp[2][8];
#pragma unroll
    for (int q = 0; q < 2; q++) {
        int cb = ((q * 256 + tid) >> 5) * 8;
#pragma unroll
        for (int j = 0; j < 8; j++)
            scp[q][j] = ((unsigned)f2bf(scs_lds[cb + j])) | ((unsigned)f2bf(scs_lds[128 + cb + j]) << 16);
    }

    float ev = 1.0f + epsp[0];
    int e0 = rp[n], e1 = rp[n + 1], deg = e1 - e0;
    const uint4* X = (const uint4*)Hin;
    int off = (tid >> 5) * 64 + (tid & 31);   // uint4 offset of chunk0 within half-slab view
    float acc[2][8];
    uint4 bufA[2], bufB[2];

    auto loadslab = [&](uint4* buf, int node) {
        const uint4* p = X + (size_t)node * 1024 + h * 32;
        buf[0] = p[off];
        buf[1] = p[512 + off];
    };
    auto addp = [&](const uint4* buf) {
#pragma unroll
        for (int q = 0; q < 2; q++) {
            float f[8]; unpack8(buf[q], f);
#pragma unroll
            for (int j = 0; j < 8; j++) {
                float sc = __builtin_bit_cast(float, scp[q][j] << 16);
                float sh = __builtin_bit_cast(float, scp[q][j] & 0xffff0000u);
                acc[q][j] += fmaxf(fmaf(f[j], sc, sh), 0.f);
            }
        }
    };

    loadslab(bufA, n);
    if (deg > 0) loadslab(bufB, colv[e0]);

#pragma unroll
    for (int q = 0; q < 2; q++) {
        float f[8]; unpack8(bufA[q], f);
#pragma unroll
        for (int j = 0; j < 8; j++) {
            float sc = __builtin_bit_cast(float, scp[q][j] << 16);
            float sh = __builtin_bit_cast(float, scp[q][j] & 0xffff0000u);
            acc[q][j] = ev * fmaxf(fmaf(f[j], sc, sh), 0.f);
        }
    }

    int i = 1;
    for (; i + 1 < deg; i += 2) {
        loadslab(bufA, colv[e0 + i]);
        addp(bufB);
        loadslab(bufB, colv[e0 + i + 1]);
        addp(bufA);
    }
    if (deg > 0) {
        if (i < deg) {
            loadslab(bufA, colv[e0 + i]);
            addp(bufB);
            addp(bufA);
        } else {
            addp(bufB);
        }
    }

    // stage half-slab to LDS: half-A-layout elem(mh,k) at ((k>>3)*32+mh)*8+(k&7)
    {
        int pos0 = (tid >> 5) * 32 + (tid & 31);
        ((uint4*)Zs)[pos0] = pack8(acc[0]);
        ((uint4*)Zs)[256 + pos0] = pack8(acc[1]);
    }
    __syncthreads();

    // MFMA: 4 waves; wave w owns 32 cols (2 B-frags) x 32 rows (2 M-tiles)
    int w = tid >> 6, lane = tid & 63, lg = lane >> 4, ln = lane & 15;
    floatx4 C[2][2];
#pragma unroll
    for (int mt = 0; mt < 2; mt++) { C[mt][0] = {0.f, 0.f, 0.f, 0.f}; C[mt][1] = {0.f, 0.f, 0.f, 0.f}; }

    for (int kb = 0; kb < 4; kb++) {
        short8 B0 = *(const short8*)&W21t[(w * 32 + ln) * 128 + kb * 32 + lg * 8];
        short8 B1 = *(const short8*)&W21t[(w * 32 + 16 + ln) * 128 + kb * 32 + lg * 8];
#pragma unroll
        for (int mt = 0; mt < 2; mt++) {
            short8 A = *(const short8*)&Zs[((kb * 4 + lg) * 32 + mt * 16 + ln) * 8];
            C[mt][0] = __builtin_amdgcn_mfma_f32_16x16x32_bf16(A, B0, C[mt][0], 0, 0, 0);
            C[mt][1] = __builtin_amdgcn_mfma_f32_16x16x32_bf16(A, B1, C[mt][1], 0, 0, 0);
        }
    }

    float fac = ev + (float)deg;
    float bsum[2], bsq[2];
    float bv[2] = {b1[w * 32 + ln] + fac * bvec[w * 32 + ln],
                   b1[w * 32 + 16 + ln] + fac * bvec[w * 32 + 16 + ln]};
#pragma unroll
    for (int nt = 0; nt < 2; nt++) {
        float s = 0.f, s2 = 0.f;
#pragma unroll
        for (int mt = 0; mt < 2; mt++)
#pragma unroll
            for (int r = 0; r < 4; r++) {
                float v = C[mt][nt][r] + bv[nt];
                C[mt][nt][r] = v;
                s += v; s2 += v * v;
            }
        bsum[nt] = s; bsq[nt] = s2;
    }
#pragma unroll
    for (int nt = 0; nt < 2; nt++) {
        bsum[nt] += __shfl_xor(bsum[nt], 16, 64);
        bsum[nt] += __shfl_xor(bsum[nt], 32, 64);
        bsq[nt] += __shfl_xor(bsq[nt], 16, 64);
        bsq[nt] += __shfl_xor(bsq[nt], 32, 64);
    }
    if (lg == 0) {
        float* sl = sums_cur + (blockIdx.x & (NSLOT - 1)) * 256;
        int c0 = w * 32 + ln;
        atomicAdd(&sl[c0], bsum[0]);
        atomicAdd(&sl[c0 + 16], bsum[1]);
        atomicAdd(&sl[128 + c0], bsq[0]);
        atomicAdd(&sl[128 + c0 + 16], bsq[1]);
    }

    // C-layout -> half-A-layout via LDS, then coalesced nontemporal store of this half's rows
    __syncthreads();
#pragma unroll
    for (int nt = 0; nt < 2; nt++) {
        int colc = w * 32 + nt * 16 + ln;
        int base = (colc >> 3) * 256 + (colc & 7);   // (kg*32 + mh)*8 + (k&7), kg=colc>>3
#pragma unroll
        for (int mt = 0; mt < 2; mt++)
#pragma unroll
            for (int r = 0; r < 4; r++) {
                int mh = mt * 16 + lg * 4 + r;
                Zs[base + mh * 8] = f2bf(C[mt][nt][r]);
            }
    }
    __syncthreads();
    {
        int pos0 = (tid >> 5) * 32 + (tid & 31);
        uint4* Hd = (uint4*)&Hout[(size_t)n * 8192];
        nt_store16(&((const uint4*)Zs)[pos0], &Hd[off + h * 32]);
        nt_store16(&((const uint4*)Zs)[256 + pos0], &Hd[512 + off + h * 32]);
    }
}

// ---------------- final: PE = sum_rows mask * (relu(bn(H3)) @ W2l + b2l) ----------------
__global__ __launch_bounds__(256, 4) void gin_mm2_last(const ushort_t* __restrict__ H, const ushort_t* __restrict__ W2t,
                                                       const float* __restrict__ b2,
                                                       const float* __restrict__ sums_prev,
                                                       const float* __restrict__ gam_prev,
                                                       const float* __restrict__ bet_prev,
                                                       const float* __restrict__ mask, float* __restrict__ out) {
    __shared__ ushort_t Hs[64 * 128];
    __shared__ float scs_lds[256];
    int tid = threadIdx.x, n = blockIdx.x;
    if (tid < 128) {
        float s = 0.f, s2 = 0.f;
#pragma unroll
        for (int k = 0; k < NSLOT; k++) {
            s += sums_prev[k * 256 + tid];
            s2 += sums_prev[k * 256 + 128 + tid];
        }
        float mean = s * (1.f / (float)ROWS);
        float var = s2 * (1.f / (float)ROWS) - mean * mean;
        float sc = gam_prev[tid] * rsqrtf(var + 1e-5f);
        scs_lds[tid] = sc;
        scs_lds[128 + tid] = bet_prev[tid] - mean * sc;
    }
    __syncthreads();

#pragma unroll
    for (int q = 0; q < 4; q++) {
        int c = q * 256 + tid;
        uint4 v = ((const uint4*)&H[(size_t)n * 8192])[c];
        float f[8]; unpack8(v, f);
        int cb = (c >> 6) * 8;
#pragma unroll
        for (int j = 0; j < 8; j++) f[j] = fmaxf(fmaf(f[j], scs_lds[cb + j], scs_lds[128 + cb + j]), 0.f);
        ((uint4*)Hs)[c] = pack8(f);
    }
    __syncthreads();

    int w = tid >> 6, lane = tid & 63, lg = lane >> 4, ln = lane & 15;
    floatx4 C[4];
#pragma unroll
    for (int mt = 0; mt < 4; mt++) C[mt] = {0.f, 0.f, 0.f, 0.f};

    for (int kb = 0; kb < 4; kb++) {
        short8 B = *(const short8*)&W2t[(w * 16 + ln) * 128 + kb * 32 + lg * 8];
#pragma unroll
        for (int mt = 0; mt < 4; mt++) {
            short8 A = *(const short8*)&Hs[((kb * 4 + lg) * 64 + mt * 16 + ln) * 8];
            C[mt] = __builtin_amdgcn_mfma_f32_16x16x32_bf16(A, B, C[mt], 0, 0, 0);
        }
    }

    int colc = w * 16 + ln;
    float bb = b2[colc];
    float pe = 0.f;
#pragma unroll
    for (int mt = 0; mt < 4; mt++)
#pragma unroll
        for (int r = 0; r < 4; r++) {
            int row = mt * 16 + lg * 4 + r;
            pe += mask[n * 64 + row] * (C[mt][r] + bb);
        }
    pe += __shfl_xor(pe, 16, 64);
    pe += __shfl_xor(pe, 32, 64);
    if (lg == 0) out[(size_t)n * 64 + colc] = pe;
}

// ---------------- host launch ----------------
extern "C" void kernel_launch(void* const* d_in, const int* in_sizes, int n_in, void* d_out, int out_size,
                              void* d_ws, size_t ws_size, hipStream_t stream) {
    const float* W    = (const float*)d_in[0];
    const float* mask = (const float*)d_in[1];
    const int* src    = (const int*)d_in[2];
    const int* dst    = (const int*)d_in[3];
    const float* eps  = (const float*)d_in[4];
    const float* W1f  = (const float*)d_in[5];
    const float* b1f  = (const float*)d_in[6];
    const float* W1r  = (const float*)d_in[7];
    const float* b1r  = (const float*)d_in[8];
    const float* gam  = (const float*)d_in[9];
    const float* bet  = (const float*)d_in[10];
    const float* W2m  = (const float*)d_in[11];
    const float* b2m  = (const float*)d_in[12];
    const float* W2l  = (const float*)d_in[13];
    const float* b2l  = (const float*)d_in[14];
    float* out = (float*)d_out;

    // workspace layout
    ushort_t* Ha   = (ushort_t*)d_ws;          // 16,777,216
    ushort_t* Hb   = Ha + 16777216;            // 16,777,216
    ushort_t* w1t0 = Hb + 16777216;            // 4096
    ushort_t* w2lt = w1t0 + 4096;              // 8192
    ushort_t* w21t = w2lt + 8192;              // 49152
    float* bvec    = (float*)(w21t + 49152);   // 384
    float* sums    = bvec + 384;               // 4 layers x NSLOT x 256 = 32768
    int* irp       = (int*)(sums + 32768);     // 2049
    int* icol      = irp + 2052;               // 16384

    // single prep dispatch: CSR + weights + sums-zero
    mega_prep<<<259, 256, 0, stream>>>(src, dst, W1f, W2l, b2m, W1r, W2m, irp, icol,
                                       w1t0, w2lt, bvec, w21t, sums);

    const int SL = NSLOT * 256;
    // layer 0 (stats -> sums slots [0])
    gin_mm1_l0<<<N_SUM, 256, 0, stream>>>(W, w1t0, b1f, eps, irp, icol, Ha, sums);
    // layers 1..3, half-node blocks
    gin_mm1_fused<<<2 * N_SUM, 256, 0, stream>>>(Ha, w21t, b1r, bvec, sums, gam, bet, eps + 1,
                                                 irp, icol, Hb, sums + SL);
    gin_mm1_fused<<<2 * N_SUM, 256, 0, stream>>>(Hb, w21t + 16384, b1r + 128, bvec + 128, sums + SL,
                                                 gam + 128, bet + 128, eps + 2, irp, icol, Ha, sums + 2 * SL);
    gin_mm1_fused<<<2 * N_SUM, 256, 0, stream>>>(Ha, w21t + 32768, b1r + 256, bvec + 256, sums + 2 * SL,
                                                 gam + 256, bet + 256, eps + 3, irp, icol, Hb, sums + 3 * SL);
    // final (consumes slots[3])
    gin_mm2_last<<<N_SUM, 256, 0, stream>>>(Hb, w2lt, b2l, sums + 3 * SL, gam + 384, bet + 384, mask, out);
}

// Round 11
// 263.737 us; speedup vs baseline: 1.2513x; 1.2513x over previous
//
#include <hip/hip_runtime.h>

#define N_SUM 2048
#define HIDD 128
#define NEDGE 16384
#define ROWS (N_SUM * 64)
#define NSLOT 16

typedef short short8 __attribute__((ext_vector_type(8)));
typedef float floatx4 __attribute__((ext_vector_type(4)));
typedef unsigned int uint4n __attribute__((ext_vector_type(4)));
typedef unsigned short ushort_t;

__device__ __forceinline__ ushort_t f2bf(float f) {
    unsigned u = __builtin_bit_cast(unsigned, f);
    u += 0x7fffu + ((u >> 16) & 1u);   // RNE
    return (ushort_t)(u >> 16);
}
__device__ __forceinline__ float bf2f(ushort_t h) {
    return __builtin_bit_cast(float, (unsigned)h << 16);
}
__device__ __forceinline__ void unpack8(uint4 v, float* f) {
    f[0] = bf2f(v.x & 0xffff); f[1] = bf2f(v.x >> 16);
    f[2] = bf2f(v.y & 0xffff); f[3] = bf2f(v.y >> 16);
    f[4] = bf2f(v.z & 0xffff); f[5] = bf2f(v.z >> 16);
    f[6] = bf2f(v.w & 0xffff); f[7] = bf2f(v.w >> 16);
}
__device__ __forceinline__ uint4 pack8(const float* f) {
    uint4 v;
    v.x = f2bf(f[0]) | ((unsigned)f2bf(f[1]) << 16);
    v.y = f2bf(f[2]) | ((unsigned)f2bf(f[3]) << 16);
    v.z = f2bf(f[4]) | ((unsigned)f2bf(f[5]) << 16);
    v.w = f2bf(f[6]) | ((unsigned)f2bf(f[7]) << 16);
    return v;
}
__device__ __forceinline__ void nt_store16(const void* src, void* dst) {
    __builtin_nontemporal_store(*(const uint4n*)src, (uint4n*)dst);
}

// ---------------- mega prep (ONE dispatch, 64 blocks x 1024 threads) ----------------
// block 0      : full CSR build, latency-batched (16 loads/thread in flight)
// blocks 1..13 : w1t0 / w2lt / bvec
// blocks 14..61: w21t = W2m @ W1r (B-fragment layout)
// blocks 62..63: zero sums (4 layers x NSLOT x 256 floats = 16384)
__global__ __launch_bounds__(1024) void mega_prep(const int* __restrict__ src, const int* __restrict__ dst,
                                                  const float* __restrict__ W1f, const float* __restrict__ W2l,
                                                  const float* __restrict__ b2m, const float* __restrict__ W1r,
                                                  const float* __restrict__ W2m,
                                                  int* __restrict__ irp, int* __restrict__ icol,
                                                  ushort_t* __restrict__ w1t0, ushort_t* __restrict__ w2lt,
                                                  float* __restrict__ bvec, ushort_t* __restrict__ w21t,
                                                  float* __restrict__ sums) {
    __shared__ int sdeg[2048];
    __shared__ int scur[2048];
    __shared__ int red[1024];
    int tid = threadIdx.x, blk = blockIdx.x;

    if (blk == 0) {
        sdeg[tid] = 0;
        sdeg[tid + 1024] = 0;
        __syncthreads();
        // batched count: all 16 loads issued before any use
        int d[16];
#pragma unroll
        for (int q = 0; q < 16; q++) d[q] = dst[q * 1024 + tid];
#pragma unroll
        for (int q = 0; q < 16; q++) atomicAdd(&sdeg[d[q]], 1);
        __syncthreads();
        // scan of 2048 (2 elems/thread)
        int a = sdeg[2 * tid], b = sdeg[2 * tid + 1];
        red[tid] = a + b;
        __syncthreads();
        for (int off = 1; off < 1024; off <<= 1) {
            int v = (tid >= off) ? red[tid - off] : 0;
            __syncthreads();
            red[tid] += v;
            __syncthreads();
        }
        int base = (tid == 0) ? 0 : red[tid - 1];
        irp[2 * tid] = base;
        irp[2 * tid + 1] = base + a;
        scur[2 * tid] = base;
        scur[2 * tid + 1] = base + a;
        if (tid == 1023) irp[2048] = red[1023];
        __syncthreads();
        // batched fill
        int s[16];
#pragma unroll
        for (int q = 0; q < 16; q++) s[q] = src[q * 1024 + tid];
#pragma unroll
        for (int q = 0; q < 16; q++) {
            int pos = atomicAdd(&scur[d[q]], 1);
            icol[pos] = s[q];
        }
    } else if (blk <= 13) {
        int idx = (blk - 1) * 1024 + tid;
        if (idx < 4096) {
            int nn = idx >> 5, k = idx & 31;
            w1t0[idx] = f2bf(k < 16 ? W1f[k * 128 + nn] : 0.f);
        } else if (idx < 4096 + 8192) {
            int r = idx - 4096;
            int nn = r >> 7, k = r & 127;
            w2lt[r] = f2bf(W2l[k * 64 + nn]);
        } else if (idx < 4096 + 8192 + 384) {
            int r = idx - 12288;
            int lm = r >> 7, c = r & 127;
            float s = 0.f;
            for (int o = 0; o < 128; o++) s += b2m[lm * 128 + o] * W1r[(size_t)lm * 16384 + o * 128 + c];
            bvec[r] = s;
        }
    } else if (blk <= 61) {
        int idx = (blk - 14) * 1024 + tid;  // 49152 total
        int lm = idx >> 14, r = idx & 16383, i = r >> 7, c = r & 127;
        const float* w2row = W2m + (size_t)lm * 16384 + i * 128;
        const float* w1col = W1r + (size_t)lm * 16384 + c;
        float s = 0.f;
#pragma unroll 8
        for (int o = 0; o < 128; o++) s += w2row[o] * w1col[o * 128];
        w21t[(size_t)lm * 16384 + c * 128 + i] = f2bf(s);
    } else {
        int idx = (blk - 62) * 1024 + tid;  // 2048 threads x 8 = 16384
#pragma unroll
        for (int q = 0; q < 8; q++) sums[idx * 8 + q] = 0.f;
    }
}

// A-layout for a 64x128 (or 64x32) bf16 tile: elem(m, k) at ((k>>3)*64 + m)*8 + (k&7)

// ---------------- layer 0: gather fp32 W + MFMA (K=16 padded to 32) ----------------
__global__ __launch_bounds__(256, 4) void gin_mm1_l0(const float* __restrict__ Xf, const ushort_t* __restrict__ W1t,
                                                     const float* __restrict__ b1, const float* __restrict__ eps,
                                                     const int* __restrict__ rp, const int* __restrict__ colv,
                                                     ushort_t* __restrict__ H, float* __restrict__ sums) {
    __shared__ ushort_t Zs[64 * 128];  // 16 KB
    int tid = threadIdx.x, n = blockIdx.x;
    float ev = 1.0f + eps[0];
    int e0 = rp[n], e1 = rp[n + 1], deg = e1 - e0;
    const float4* X = (const float4*)Xf;

    float4 sA, sB;
    sA = X[(size_t)n * 256 + tid];
    if (deg > 0) sB = X[(size_t)colv[e0] * 256 + tid];
    float4 a;
    a.x = sA.x * ev; a.y = sA.y * ev; a.z = sA.z * ev; a.w = sA.w * ev;
    int i = 1;
    for (; i + 1 < deg; i += 2) {
        sA = X[(size_t)colv[e0 + i] * 256 + tid];
        a.x += sB.x; a.y += sB.y; a.z += sB.z; a.w += sB.w;
        sB = X[(size_t)colv[e0 + i + 1] * 256 + tid];
        a.x += sA.x; a.y += sA.y; a.z += sA.z; a.w += sA.w;
    }
    if (deg > 0) {
        if (i < deg) {
            sA = X[(size_t)colv[e0 + i] * 256 + tid];
            a.x += sB.x; a.y += sB.y; a.z += sB.z; a.w += sB.w;
            a.x += sA.x; a.y += sA.y; a.z += sA.z; a.w += sA.w;
        } else {
            a.x += sB.x; a.y += sB.y; a.z += sB.z; a.w += sB.w;
        }
    }

    {
        int m = tid >> 2, k0 = (tid & 3) * 4;
        int addr = ((k0 >> 3) * 64 + m) * 8 + (k0 & 7);
        uint2 pv;
        pv.x = f2bf(a.x) | ((unsigned)f2bf(a.y) << 16);
        pv.y = f2bf(a.z) | ((unsigned)f2bf(a.w) << 16);
        *(uint2*)&Zs[addr] = pv;
        *(uint2*)&Zs[1024 + tid * 4] = make_uint2(0u, 0u);
    }
    __syncthreads();

    int w = tid >> 6, lane = tid & 63, lg = lane >> 4, ln = lane & 15;
    floatx4 C[4][2];
#pragma unroll
    for (int mt = 0; mt < 4; mt++) { C[mt][0] = {0.f, 0.f, 0.f, 0.f}; C[mt][1] = {0.f, 0.f, 0.f, 0.f}; }

    {
        short8 B0 = *(const short8*)&W1t[(w * 32 + ln) * 32 + lg * 8];
        short8 B1 = *(const short8*)&W1t[(w * 32 + 16 + ln) * 32 + lg * 8];
#pragma unroll
        for (int mt = 0; mt < 4; mt++) {
            short8 A = *(const short8*)&Zs[(lg * 64 + mt * 16 + ln) * 8];
            C[mt][0] = __builtin_amdgcn_mfma_f32_16x16x32_bf16(A, B0, C[mt][0], 0, 0, 0);
            C[mt][1] = __builtin_amdgcn_mfma_f32_16x16x32_bf16(A, B1, C[mt][1], 0, 0, 0);
        }
    }

    float bsum[2], bsq[2];
    float bv[2] = {b1[w * 32 + ln], b1[w * 32 + 16 + ln]};
#pragma unroll
    for (int nt = 0; nt < 2; nt++) {
        float s = 0.f, s2 = 0.f;
#pragma unroll
        for (int mt = 0; mt < 4; mt++)
#pragma unroll
            for (int r = 0; r < 4; r++) {
                float v = C[mt][nt][r] + bv[nt];
                C[mt][nt][r] = v;
                s += v; s2 += v * v;
            }
        bsum[nt] = s; bsq[nt] = s2;
    }
#pragma unroll
    for (int nt = 0; nt < 2; nt++) {
        bsum[nt] += __shfl_xor(bsum[nt], 16, 64);
        bsum[nt] += __shfl_xor(bsum[nt], 32, 64);
        bsq[nt] += __shfl_xor(bsq[nt], 16, 64);
        bsq[nt] += __shfl_xor(bsq[nt], 32, 64);
    }
    if (lg == 0) {
        float* sl = sums + (n & (NSLOT - 1)) * 256;
        int c0 = w * 32 + ln;
        atomicAdd(&sl[c0], bsum[0]);
        atomicAdd(&sl[c0 + 16], bsum[1]);
        atomicAdd(&sl[128 + c0], bsq[0]);
        atomicAdd(&sl[128 + c0 + 16], bsq[1]);
    }
    __syncthreads();
#pragma unroll
    for (int nt = 0; nt < 2; nt++) {
        int colc = w * 32 + nt * 16 + ln;
        int base = (colc >> 3) * 512 + (colc & 7);
#pragma unroll
        for (int mt = 0; mt < 4; mt++)
#pragma unroll
            for (int r = 0; r < 4; r++) {
                int row = mt * 16 + lg * 4 + r;
                Zs[base + row * 8] = f2bf(C[mt][nt][r]);
            }
    }
    __syncthreads();
#pragma unroll
    for (int q = 0; q < 4; q++)
        nt_store16(&((const uint4*)Zs)[q * 256 + tid], &((uint4*)&H[(size_t)n * 8192])[q * 256 + tid]);
}

// ---------------- fused layers 1..3 (512 threads, scalar math, 2-deep pipeline) ----------------
__global__ __launch_bounds__(512, 4) void gin_mm1_fused(const ushort_t* __restrict__ Hin,
                                                        const ushort_t* __restrict__ W21t,
                                                        const float* __restrict__ b1, const float* __restrict__ bvec,
                                                        const float* __restrict__ sums_prev,
                                                        const float* __restrict__ gam_prev,
                                                        const float* __restrict__ bet_prev,
                                                        const float* __restrict__ epsp,
                                                        const int* __restrict__ rp, const int* __restrict__ colv,
                                                        ushort_t* __restrict__ Hout, float* __restrict__ sums_cur) {
    __shared__ ushort_t Zs[64 * 128];   // 16 KB
    __shared__ float scs_lds[256];      // 1 KB
    int tid = threadIdx.x, n = blockIdx.x;
    if (tid < 128) {
        float s = 0.f, s2 = 0.f;
#pragma unroll
        for (int k = 0; k < NSLOT; k++) {
            s += sums_prev[k * 256 + tid];
            s2 += sums_prev[k * 256 + 128 + tid];
        }
        float mean = s * (1.f / (float)ROWS);
        float var = s2 * (1.f / (float)ROWS) - mean * mean;
        float sc = gam_prev[tid] * rsqrtf(var + 1e-5f);
        scs_lds[tid] = sc;
        scs_lds[128 + tid] = bet_prev[tid] - mean * sc;
    }
    __syncthreads();

    unsigned scp[2][8];
#pragma unroll
    for (int q = 0; q < 2; q++) {
        int cb = ((q * 512 + tid) >> 6) * 8;
#pragma unroll
        for (int j = 0; j < 8; j++)
            scp[q][j] = ((unsigned)f2bf(scs_lds[cb + j])) | ((unsigned)f2bf(scs_lds[128 + cb + j]) << 16);
    }

    float ev = 1.0f + epsp[0];
    int e0 = rp[n], e1 = rp[n + 1], deg = e1 - e0;
    const uint4* X = (const uint4*)Hin;
    float acc[2][8];
    uint4 bufA[2], bufB[2];

    auto loadslab = [&](uint4* buf, int node) {
        const uint4* p = X + (size_t)node * 1024;
        buf[0] = p[tid];
        buf[1] = p[512 + tid];
    };
    auto addp = [&](const uint4* buf) {
#pragma unroll
        for (int q = 0; q < 2; q++) {
            float f[8]; unpack8(buf[q], f);
#pragma unroll
            for (int j = 0; j < 8; j++) {
                float sc = __builtin_bit_cast(float, scp[q][j] << 16);
                float sh = __builtin_bit_cast(float, scp[q][j] & 0xffff0000u);
                acc[q][j] += fmaxf(fmaf(f[j], sc, sh), 0.f);
            }
        }
    };

    loadslab(bufA, n);
    if (deg > 0) loadslab(bufB, colv[e0]);

#pragma unroll
    for (int q = 0; q < 2; q++) {
        float f[8]; unpack8(bufA[q], f);
#pragma unroll
        for (int j = 0; j < 8; j++) {
            float sc = __builtin_bit_cast(float, scp[q][j] << 16);
            float sh = __builtin_bit_cast(float, scp[q][j] & 0xffff0000u);
            acc[q][j] = ev * fmaxf(fmaf(f[j], sc, sh), 0.f);
        }
    }

    int i = 1;
    for (; i + 1 < deg; i += 2) {
        loadslab(bufA, colv[e0 + i]);
        addp(bufB);
        loadslab(bufB, colv[e0 + i + 1]);
        addp(bufA);
    }
    if (deg > 0) {
        if (i < deg) {
            loadslab(bufA, colv[e0 + i]);
            addp(bufB);
            addp(bufA);
        } else {
            addp(bufB);
        }
    }

#pragma unroll
    for (int q = 0; q < 2; q++) ((uint4*)Zs)[q * 512 + tid] = pack8(acc[q]);
    __syncthreads();

    int w = tid >> 6, lane = tid & 63, lg = lane >> 4, ln = lane & 15;
    floatx4 C[4];
#pragma unroll
    for (int mt = 0; mt < 4; mt++) C[mt] = {0.f, 0.f, 0.f, 0.f};

    for (int kb = 0; kb < 4; kb++) {
        short8 B = *(const short8*)&W21t[(w * 16 + ln) * 128 + kb * 32 + lg * 8];
#pragma unroll
        for (int mt = 0; mt < 4; mt++) {
            short8 A = *(const short8*)&Zs[((kb * 4 + lg) * 64 + mt * 16 + ln) * 8];
            C[mt] = __builtin_amdgcn_mfma_f32_16x16x32_bf16(A, B, C[mt], 0, 0, 0);
        }
    }

    float fac = ev + (float)deg;
    int c0 = w * 16 + ln;
    float bv = b1[c0] + fac * bvec[c0];
    float s = 0.f, s2 = 0.f;
#pragma unroll
    for (int mt = 0; mt < 4; mt++)
#pragma unroll
        for (int r = 0; r < 4; r++) {
            float v = C[mt][r] + bv;
            C[mt][r] = v;
            s += v; s2 += v * v;
        }
    s += __shfl_xor(s, 16, 64);
    s += __shfl_xor(s, 32, 64);
    s2 += __shfl_xor(s2, 16, 64);
    s2 += __shfl_xor(s2, 32, 64);
    if (lg == 0) {
        float* sl = sums_cur + (n & (NSLOT - 1)) * 256;
        atomicAdd(&sl[c0], s);
        atomicAdd(&sl[128 + c0], s2);
    }

    __syncthreads();
    {
        int base = (c0 >> 3) * 512 + (c0 & 7);
#pragma unroll
        for (int mt = 0; mt < 4; mt++)
#pragma unroll
            for (int r = 0; r < 4; r++) {
                int row = mt * 16 + lg * 4 + r;
                Zs[base + row * 8] = f2bf(C[mt][r]);
            }
    }
    __syncthreads();
#pragma unroll
    for (int q = 0; q < 2; q++)
        nt_store16(&((const uint4*)Zs)[q * 512 + tid], &((uint4*)&Hout[(size_t)n * 8192])[q * 512 + tid]);
}

// ---------------- final: PE = sum_rows mask * (relu(bn(H3)) @ W2l + b2l) ----------------
__global__ __launch_bounds__(256, 4) void gin_mm2_last(const ushort_t* __restrict__ H, const ushort_t* __restrict__ W2t,
                                                       const float* __restrict__ b2,
                                                       const float* __restrict__ sums_prev,
                                                       const float* __restrict__ gam_prev,
                                                       const float* __restrict__ bet_prev,
                                                       const float* __restrict__ mask, float* __restrict__ out) {
    __shared__ ushort_t Hs[64 * 128];
    __shared__ float scs_lds[256];
    int tid = threadIdx.x, n = blockIdx.x;
    if (tid < 128) {
        float s = 0.f, s2 = 0.f;
#pragma unroll
        for (int k = 0; k < NSLOT; k++) {
            s += sums_prev[k * 256 + tid];
            s2 += sums_prev[k * 256 + 128 + tid];
        }
        float mean = s * (1.f / (float)ROWS);
        float var = s2 * (1.f / (float)ROWS) - mean * mean;
        float sc = gam_prev[tid] * rsqrtf(var + 1e-5f);
        scs_lds[tid] = sc;
        scs_lds[128 + tid] = bet_prev[tid] - mean * sc;
    }
    __syncthreads();

#pragma unroll
    for (int q = 0; q < 4; q++) {
        int c = q * 256 + tid;
        uint4 v = ((const uint4*)&H[(size_t)n * 8192])[c];
        float f[8]; unpack8(v, f);
        int cb = (c >> 6) * 8;
#pragma unroll
        for (int j = 0; j < 8; j++) f[j] = fmaxf(fmaf(f[j], scs_lds[cb + j], scs_lds[128 + cb + j]), 0.f);
        ((uint4*)Hs)[c] = pack8(f);
    }
    __syncthreads();

    int w = tid >> 6, lane = tid & 63, lg = lane >> 4, ln = lane & 15;
    floatx4 C[4];
#pragma unroll
    for (int mt = 0; mt < 4; mt++) C[mt] = {0.f, 0.f, 0.f, 0.f};

    for (int kb = 0; kb < 4; kb++) {
        short8 B = *(const short8*)&W2t[(w * 16 + ln) * 128 + kb * 32 + lg * 8];
#pragma unroll
        for (int mt = 0; mt < 4; mt++) {
            short8 A = *(const short8*)&Hs[((kb * 4 + lg) * 64 + mt * 16 + ln) * 8];
            C[mt] = __builtin_amdgcn_mfma_f32_16x16x32_bf16(A, B, C[mt], 0, 0, 0);
        }
    }

    int colc = w * 16 + ln;
    float bb = b2[colc];
    float pe = 0.f;
#pragma unroll
    for (int mt = 0; mt < 4; mt++)
#pragma unroll
        for (int r = 0; r < 4; r++) {
            int row = mt * 16 + lg * 4 + r;
            pe += mask[n * 64 + row] * (C[mt][r] + bb);
        }
    pe += __shfl_xor(pe, 16, 64);
    pe += __shfl_xor(pe, 32, 64);
    if (lg == 0) out[(size_t)n * 64 + colc] = pe;
}

// ---------------- host launch ----------------
extern "C" void kernel_launch(void* const* d_in, const int* in_sizes, int n_in, void* d_out, int out_size,
                              void* d_ws, size_t ws_size, hipStream_t stream) {
    const float* W    = (const float*)d_in[0];
    const float* mask = (const float*)d_in[1];
    const int* src    = (const int*)d_in[2];
    const int* dst    = (const int*)d_in[3];
    const float* eps  = (const float*)d_in[4];
    const float* W1f  = (const float*)d_in[5];
    const float* b1f  = (const float*)d_in[6];
    const float* W1r  = (const float*)d_in[7];
    const float* b1r  = (const float*)d_in[8];
    const float* gam  = (const float*)d_in[9];
    const float* bet  = (const float*)d_in[10];
    const float* W2m  = (const float*)d_in[11];
    const float* b2m  = (const float*)d_in[12];
    const float* W2l  = (const float*)d_in[13];
    const float* b2l  = (const float*)d_in[14];
    float* out = (float*)d_out;

    // workspace layout
    ushort_t* Ha   = (ushort_t*)d_ws;          // 16,777,216
    ushort_t* Hb   = Ha + 16777216;            // 16,777,216
    ushort_t* w1t0 = Hb + 16777216;            // 4096
    ushort_t* w2lt = w1t0 + 4096;              // 8192
    ushort_t* w21t = w2lt + 8192;              // 49152
    float* bvec    = (float*)(w21t + 49152);   // 384
    float* sums    = bvec + 384;               // 4 layers x NSLOT x 256 = 16384
    int* irp       = (int*)(sums + 16384);     // 2049 (pad to 2052)
    int* icol      = irp + 2052;               // 16384

    // single prep dispatch: CSR (1 block, batched) + weights + sums-zero
    mega_prep<<<64, 1024, 0, stream>>>(src, dst, W1f, W2l, b2m, W1r, W2m, irp, icol,
                                       w1t0, w2lt, bvec, w21t, sums);

    const int SL = NSLOT * 256;
    // layer 0 (stats -> sums slots [0])
    gin_mm1_l0<<<N_SUM, 256, 0, stream>>>(W, w1t0, b1f, eps, irp, icol, Ha, sums);
    // layers 1..3 (consume slots[l-1], produce slots[l])
    gin_mm1_fused<<<N_SUM, 512, 0, stream>>>(Ha, w21t, b1r, bvec, sums, gam, bet, eps + 1,
                                             irp, icol, Hb, sums + SL);
    gin_mm1_fused<<<N_SUM, 512, 0, stream>>>(Hb, w21t + 16384, b1r + 128, bvec + 128, sums + SL,
                                             gam + 128, bet + 128, eps + 2, irp, icol, Ha, sums + 2 * SL);
    gin_mm1_fused<<<N_SUM, 512, 0, stream>>>(Ha, w21t + 32768, b1r + 256, bvec + 256, sums + 2 * SL,
                                             gam + 256, bet + 256, eps + 3, irp, icol, Hb, sums + 3 * SL);
    // final (consumes slots[3])
    gin_mm2_last<<<N_SUM, 256, 0, stream>>>(Hb, w2lt, b2l, sums + 3 * SL, gam + 384, bet + 384, mask, out);
}